// Round 6
// baseline (111.577 us; speedup 1.0000x reference)
//
#include <hip/hip_runtime.h>
#include <hip/hip_bf16.h>

#define NN 8192
#define SD 512
#define HID 128
#define DE 128
#define KP1 11
#define EPSF 0.001f
#define NSPLIT 32
#define NCHUNK NSPLIT        // 32 partial lists per row
#define TILE 32
#define NTILE ((NN / NSPLIT) / TILE)   // 8 tiles of 32 candidates per block

using short8 = __attribute__((ext_vector_type(8))) short;
using f32x4 = __attribute__((ext_vector_type(4))) float;

__device__ inline ushort f2bf(float f) {
    __hip_bfloat16 b = __float2bfloat16(f);
    return *reinterpret_cast<ushort*>(&b);
}
__device__ inline float bf2f(ushort u) {
    unsigned v = (unsigned)u << 16;
    union { unsigned u; float f; } c; c.u = v; return c.f;
}

// ---------------- Kernel 0: pre-split W1, W2 into hi/lo bf16 (layout unchanged: [col][k])
__global__ __launch_bounds__(256) void wsplit_kernel(
    const float* __restrict__ W1, const float* __restrict__ W2,
    ushort* __restrict__ W1h, ushort* __restrict__ W1l,
    ushort* __restrict__ W2h, ushort* __restrict__ W2l)
{
    const int bid = blockIdx.x;
    const float* src; ushort *dh, *dl; int base;
    if (bid < 64) { src = W1; dh = W1h; dl = W1l; base = bid * 1024; }
    else          { src = W2; dh = W2h; dl = W2l; base = (bid - 64) * 1024; }
    const int i = base + threadIdx.x * 4;
    float4 f = *reinterpret_cast<const float4*>(src + i);
    ushort h[4], lo[4];
    float fv[4] = {f.x, f.y, f.z, f.w};
#pragma unroll
    for (int j = 0; j < 4; ++j) {
        h[j] = f2bf(fv[j]);
        lo[j] = f2bf(fv[j] - bf2f(h[j]));
    }
    *reinterpret_cast<uint2*>(dh + i) = *reinterpret_cast<uint2*>(h);
    *reinterpret_cast<uint2*>(dl + i) = *reinterpret_cast<uint2*>(lo);
}

// ---------------- Kernel 1: split-bf16 MFMA MLP. Block = 32 rows x 128 cols, 4 waves.
// Outputs: xb = bf16(x), xb2 = bf16(-2x) (exact), sqb = ||bf16(x)||^2
__global__ __launch_bounds__(256) void mlp_kernel(
    const float* __restrict__ s, const ushort* __restrict__ W1h,
    const ushort* __restrict__ W1l, const float* __restrict__ b1,
    const ushort* __restrict__ W2h, const ushort* __restrict__ W2l,
    const float* __restrict__ b2, __hip_bfloat16* __restrict__ xb,
    __hip_bfloat16* __restrict__ xb2, float* __restrict__ sqb)
{
    __shared__ __align__(16) ushort sbh[2][32 * 32];
    __shared__ __align__(16) ushort sbl[2][32 * 32];
    __shared__ __align__(16) ushort hbh[32 * 128];
    __shared__ __align__(16) ushort hbl[32 * 128];
    __shared__ __align__(16) ushort xtile[32 * 128];
    __shared__ __align__(16) ushort xtile2[32 * 128];
    __shared__ float sqpart[4 * 32];

    const int t = threadIdx.x;
    const int w = t >> 6, l = t & 63;
    const int lc = l & 15, c4 = l >> 4;
    const int rb = blockIdx.x * 32;
    const int cb = w * 32;

    const int srow = t >> 3, skq = t & 7;
    const int ssl = ((skq >> 1) + (srow >> 2)) & 3;
    const int sByte = srow * 64 + (ssl ^ (srow & 3)) * 16 + (skq & 1) * 8;
    const float* sgbase = s + (size_t)(rb + srow) * SD + skq * 4;

    float4 sf;
#define STAGE_LOAD_S(kt_) sf = *reinterpret_cast<const float4*>(sgbase + (kt_) * 32)
#define STAGE_WRITE_S(b_) do { \
    float fv_[4] = {sf.x, sf.y, sf.z, sf.w}; \
    ushort h_[4], lo_[4]; \
    _Pragma("unroll") \
    for (int j_ = 0; j_ < 4; ++j_) { \
        h_[j_] = f2bf(fv_[j_]); \
        lo_[j_] = f2bf(fv_[j_] - bf2f(h_[j_])); \
    } \
    *reinterpret_cast<uint2*>(reinterpret_cast<char*>(sbh[b_]) + sByte) = *reinterpret_cast<uint2*>(h_); \
    *reinterpret_cast<uint2*>(reinterpret_cast<char*>(sbl[b_]) + sByte) = *reinterpret_cast<uint2*>(lo_); \
} while (0)

    int aByte[2];
#pragma unroll
    for (int rt = 0; rt < 2; ++rt) {
        int row = rt * 16 + lc;
        int sl = ((c4 + (row >> 2)) & 3) ^ (row & 3);
        aByte[rt] = row * 64 + sl * 16;
    }

    const ushort* w1hp[2]; const ushort* w1lp[2];
#pragma unroll
    for (int ct = 0; ct < 2; ++ct) {
        int col = cb + ct * 16 + lc;
        w1hp[ct] = W1h + (size_t)col * SD + c4 * 8;
        w1lp[ct] = W1l + (size_t)col * SD + c4 * 8;
    }

    f32x4 acc1[2][2];
#pragma unroll
    for (int rt = 0; rt < 2; ++rt)
#pragma unroll
        for (int ct = 0; ct < 2; ++ct) acc1[rt][ct] = {0.f, 0.f, 0.f, 0.f};

    STAGE_LOAD_S(0);
    STAGE_WRITE_S(0);
    short8 bh[2], bl[2], nbh[2], nbl[2];
#pragma unroll
    for (int ct = 0; ct < 2; ++ct) {
        bh[ct] = *reinterpret_cast<const short8*>(w1hp[ct]);
        bl[ct] = *reinterpret_cast<const short8*>(w1lp[ct]);
    }

    for (int kt = 0; kt < 16; ++kt) {
        __syncthreads();
        if (kt < 15) STAGE_LOAD_S(kt + 1);
        short8 ah[2], al[2];
#pragma unroll
        for (int rt = 0; rt < 2; ++rt) {
            ah[rt] = *reinterpret_cast<const short8*>(
                reinterpret_cast<char*>(sbh[kt & 1]) + aByte[rt]);
            al[rt] = *reinterpret_cast<const short8*>(
                reinterpret_cast<char*>(sbl[kt & 1]) + aByte[rt]);
        }
        if (kt < 15) {
#pragma unroll
            for (int ct = 0; ct < 2; ++ct) {
                nbh[ct] = *reinterpret_cast<const short8*>(w1hp[ct] + (kt + 1) * 32);
                nbl[ct] = *reinterpret_cast<const short8*>(w1lp[ct] + (kt + 1) * 32);
            }
        }
#pragma unroll
        for (int rt = 0; rt < 2; ++rt)
#pragma unroll
            for (int ct = 0; ct < 2; ++ct) {
                acc1[rt][ct] = __builtin_amdgcn_mfma_f32_16x16x32_bf16(ah[rt], bh[ct], acc1[rt][ct], 0, 0, 0);
                acc1[rt][ct] = __builtin_amdgcn_mfma_f32_16x16x32_bf16(ah[rt], bl[ct], acc1[rt][ct], 0, 0, 0);
                acc1[rt][ct] = __builtin_amdgcn_mfma_f32_16x16x32_bf16(al[rt], bh[ct], acc1[rt][ct], 0, 0, 0);
            }
        if (kt < 15) {
            STAGE_WRITE_S((kt + 1) & 1);
#pragma unroll
            for (int ct = 0; ct < 2; ++ct) { bh[ct] = nbh[ct]; bl[ct] = nbl[ct]; }
        }
    }

    float b1v[2];
#pragma unroll
    for (int ct = 0; ct < 2; ++ct) b1v[ct] = b1[cb + ct * 16 + lc];
#pragma unroll
    for (int rt = 0; rt < 2; ++rt)
#pragma unroll
        for (int ct = 0; ct < 2; ++ct)
#pragma unroll
            for (int reg = 0; reg < 4; ++reg) {
                float v = fmaxf(acc1[rt][ct][reg] + b1v[ct], 0.f);
                ushort hh = f2bf(v);
                ushort hl = f2bf(v - bf2f(hh));
                int row = rt * 16 + c4 * 4 + reg;
                int kcol = cb + ct * 16 + lc;
                int sl = (kcol >> 3) ^ (row & 15);
                int byte = row * 256 + sl * 16 + (kcol & 7) * 2;
                *reinterpret_cast<ushort*>(reinterpret_cast<char*>(hbh) + byte) = hh;
                *reinterpret_cast<ushort*>(reinterpret_cast<char*>(hbl) + byte) = hl;
            }
    __syncthreads();

    f32x4 acc2[2][2];
#pragma unroll
    for (int rt = 0; rt < 2; ++rt)
#pragma unroll
        for (int ct = 0; ct < 2; ++ct) acc2[rt][ct] = {0.f, 0.f, 0.f, 0.f};

#pragma unroll
    for (int kt = 0; kt < 4; ++kt) {
        short8 ah[2], al[2];
#pragma unroll
        for (int rt = 0; rt < 2; ++rt) {
            int row = rt * 16 + lc;
            int sl = (kt * 4 + c4) ^ (row & 15);
            int byte = row * 256 + sl * 16;
            ah[rt] = *reinterpret_cast<const short8*>(reinterpret_cast<char*>(hbh) + byte);
            al[rt] = *reinterpret_cast<const short8*>(reinterpret_cast<char*>(hbl) + byte);
        }
        short8 wh[2], wl[2];
#pragma unroll
        for (int ct = 0; ct < 2; ++ct) {
            int col = cb + ct * 16 + lc;
            wh[ct] = *reinterpret_cast<const short8*>(W2h + (size_t)col * HID + kt * 32 + c4 * 8);
            wl[ct] = *reinterpret_cast<const short8*>(W2l + (size_t)col * HID + kt * 32 + c4 * 8);
        }
#pragma unroll
        for (int rt = 0; rt < 2; ++rt)
#pragma unroll
            for (int ct = 0; ct < 2; ++ct) {
                acc2[rt][ct] = __builtin_amdgcn_mfma_f32_16x16x32_bf16(ah[rt], wh[ct], acc2[rt][ct], 0, 0, 0);
                acc2[rt][ct] = __builtin_amdgcn_mfma_f32_16x16x32_bf16(ah[rt], wl[ct], acc2[rt][ct], 0, 0, 0);
                acc2[rt][ct] = __builtin_amdgcn_mfma_f32_16x16x32_bf16(al[rt], wh[ct], acc2[rt][ct], 0, 0, 0);
            }
    }

    float b2v[2];
#pragma unroll
    for (int ct = 0; ct < 2; ++ct) b2v[ct] = b2[cb + ct * 16 + lc];
    float p[8];
#pragma unroll
    for (int j = 0; j < 8; ++j) p[j] = 0.f;
#pragma unroll
    for (int rt = 0; rt < 2; ++rt)
#pragma unroll
        for (int ct = 0; ct < 2; ++ct)
#pragma unroll
            for (int reg = 0; reg < 4; ++reg) {
                float v = acc2[rt][ct][reg] + b2v[ct];
                ushort xv = f2bf(v);
                float xf = bf2f(xv);
                p[rt * 4 + reg] = fmaf(xf, xf, p[rt * 4 + reg]);
                int row = rt * 16 + c4 * 4 + reg;
                int e = cb + ct * 16 + lc;
                xtile[row * 128 + e] = xv;
                xtile2[row * 128 + e] = f2bf(-2.f * xf);   // exact: -2*bf16 representable
            }
#pragma unroll
    for (int j = 0; j < 8; ++j) {
#pragma unroll
        for (int off = 8; off >= 1; off >>= 1) p[j] += __shfl_xor(p[j], off, 16);
    }
    if (lc == 0) {
#pragma unroll
        for (int rt = 0; rt < 2; ++rt)
#pragma unroll
            for (int reg = 0; reg < 4; ++reg)
                sqpart[w * 32 + rt * 16 + c4 * 4 + reg] = p[rt * 4 + reg];
    }
    __syncthreads();
    if (t < 32)
        sqb[rb + t] = sqpart[t] + sqpart[32 + t] + sqpart[64 + t] + sqpart[96 + t];
    const short8* xsv = reinterpret_cast<const short8*>(xtile);
    short8* xg = reinterpret_cast<short8*>(reinterpret_cast<ushort*>(xb) + (size_t)rb * DE);
    xg[t] = xsv[t];
    xg[t + 256] = xsv[t + 256];
    const short8* xsv2 = reinterpret_cast<const short8*>(xtile2);
    short8* xg2 = reinterpret_cast<short8*>(reinterpret_cast<ushort*>(xb2) + (size_t)rb * DE);
    xg2[t] = xsv2[t];
    xg2[t + 256] = xsv2[t + 256];
}

// ---------------- Kernel 2: per-row top-11 of d2' = sq[c] - 2*dot, via MFMA with
// A = -2x (xs2), C-in = sq[c]. 32 queries/wave, 32-cand double-buffered LDS tiles,
// med3 sorted insert. 2048 blocks for ~6-8 blocks/CU residency.
__global__ __launch_bounds__(256, 6) void knn_kernel(
    const ushort* __restrict__ xs, const ushort* __restrict__ xs2,
    const float* __restrict__ sqb, float* __restrict__ part)
{
    __shared__ __align__(16) ushort lbuf[2][TILE * DE];   // 2 x 8KB (merge buffer overlays)
    __shared__ __align__(16) float sqs[NN / NSPLIT];      // 1KB

    const int bid = blockIdx.x;              // 2048 = 64 row-groups x 32 cand-splits
    const int rid = bid >> 5, cid = bid & 31;
    const int t = threadIdx.x;
    const int w = t >> 6, l = t & 63;
    const int q16 = l & 15, lg = l >> 4;
    const int kk = lg * 8;
    const int qb = rid * 128 + w * 32;
    const int cstart = cid * (NN / NSPLIT);  // 256 candidates per block

    // B-frags for the wave's 2 query sub-tiles (held in regs)
    short8 bq[2][4];
#pragma unroll
    for (int qs = 0; qs < 2; ++qs)
#pragma unroll
        for (int kb = 0; kb < 4; ++kb)
            bq[qs][kb] = *reinterpret_cast<const short8*>(
                xs + (size_t)(qb + qs * 16 + q16) * DE + kb * 32 + kk);

    float m[2][KP1];
#pragma unroll
    for (int qs = 0; qs < 2; ++qs)
#pragma unroll
        for (int j = 0; j < KP1; ++j) m[qs][j] = 1e30f;

#define INS(qs_, v_) do { \
    float d2_ = (v_); \
    _Pragma("unroll") \
    for (int j_ = KP1 - 1; j_ >= 1; --j_) \
        m[qs_][j_] = __builtin_amdgcn_fmed3f(d2_, m[qs_][j_ - 1], m[qs_][j_]); \
    m[qs_][0] = fminf(d2_, m[qs_][0]); \
} while (0)

    // stage sq for the block's candidate range once (256 floats)
    if (t < 64)
        reinterpret_cast<float4*>(sqs)[t] =
            reinterpret_cast<const float4*>(sqb + cstart)[t];

    // staging: thread t owns 2 16B slots s = t, t+256 of the 512-slot (8KB) tile
    int gIdx[2], dIdx[2];
#pragma unroll
    for (int i = 0; i < 2; ++i) {
        int sl = t + 256 * i;
        int row = sl >> 4, col = sl & 15;
        gIdx[i] = row * DE + col * 8;                       // ushort units
        dIdx[i] = (row * 16 + (col ^ (row & 7))) * 8;
    }
    // A-frag base indices (row = q16 within a 16-cand subtile)
    int aIdx[4];
#pragma unroll
    for (int kb = 0; kb < 4; ++kb)
        aIdx[kb] = (q16 * 16 + ((kb * 4 + lg) ^ (q16 & 7))) * 8;

    short8 st[2];
#define STAGE_LOAD(tt_) do { \
    const ushort* sb_ = xs2 + (size_t)(cstart + (tt_) * TILE) * DE; \
    st[0] = *reinterpret_cast<const short8*>(sb_ + gIdx[0]); \
    st[1] = *reinterpret_cast<const short8*>(sb_ + gIdx[1]); \
} while (0)
#define STAGE_WRITE(nb_) do { \
    *reinterpret_cast<short8*>(&lbuf[nb_][dIdx[0]]) = st[0]; \
    *reinterpret_cast<short8*>(&lbuf[nb_][dIdx[1]]) = st[1]; \
} while (0)

    STAGE_LOAD(0);
    STAGE_WRITE(0);

    for (int tt = 0; tt < NTILE; ++tt) {
        __syncthreads();                     // publishes lbuf[tt&1] (and sqs on tt=0)
        if (tt + 1 < NTILE) STAGE_LOAD(tt + 1);
        const ushort* lb = lbuf[tt & 1];
#pragma unroll
        for (int cs = 0; cs < 2; ++cs) {     // 16-cand subtiles
            short8 fa[4];
#pragma unroll
            for (int kb = 0; kb < 4; ++kb)
                fa[kb] = *reinterpret_cast<const short8*>(lb + cs * 2048 + aIdx[kb]);
            float4 sv = *reinterpret_cast<const float4*>(sqs + tt * TILE + cs * 16 + lg * 4);
#pragma unroll
            for (int qs = 0; qs < 2; ++qs) {
                f32x4 acc = {sv.x, sv.y, sv.z, sv.w};   // C-in = sq[c]; A = -2x
#pragma unroll
                for (int kb = 0; kb < 4; ++kb)
                    acc = __builtin_amdgcn_mfma_f32_16x16x32_bf16(fa[kb], bq[qs][kb], acc, 0, 0, 0);
                INS(qs, acc[0]);
                INS(qs, acc[1]);
                INS(qs, acc[2]);
                INS(qs, acc[3]);
            }
        }
        if (tt + 1 < NTILE) STAGE_WRITE((tt + 1) & 1);  // buffer freed by this iter's sync
    }
#undef STAGE_LOAD
#undef STAGE_WRITE
#undef INS

    // ---- in-kernel lane-group merge, 2 phases (qs) to fit the 11KB buffer in lbuf
    float* mb = reinterpret_cast<float*>(lbuf);   // [4w][4lg][11][16] floats = 11264 B
#pragma unroll
    for (int qs = 0; qs < 2; ++qs) {
        __syncthreads();                     // lbuf free / previous phase done
#pragma unroll
        for (int j = 0; j < KP1; ++j)
            mb[((w * 4 + lg) * KP1 + j) * 16 + q16] = m[qs][j];
        __syncthreads();
        if (l < 16) {                        // lanes 0..15: q16 == l
            float mm[KP1];
#pragma unroll
            for (int j = 0; j < KP1; ++j)
                mm[j] = mb[((w * 4 + 0) * KP1 + j) * 16 + l];
#pragma unroll
            for (int g = 1; g < 4; ++g)
#pragma unroll
                for (int j = 0; j < KP1; ++j) {
                    float d2 = mb[((w * 4 + g) * KP1 + j) * 16 + l];
#pragma unroll
                    for (int jj = KP1 - 1; jj >= 1; --jj)
                        mm[jj] = __builtin_amdgcn_fmed3f(d2, mm[jj - 1], mm[jj]);
                    mm[0] = fminf(d2, mm[0]);
                }
            const int q = qb + qs * 16 + l;
#pragma unroll
            for (int j = 0; j < KP1; ++j)
                part[(size_t)(cid * KP1 + j) * NN + q] = mm[j];
        }
    }
}

// ---------------- Kernel 3: merge 32 partial top-11 lists -> sumk[row]; block partial sums
__global__ __launch_bounds__(256) void merge_kernel(
    const float* __restrict__ part, const float* __restrict__ sqb,
    float* __restrict__ sumk, float* __restrict__ psum)
{
    const int row = blockIdx.x * 256 + threadIdx.x;
    float m[KP1];
#pragma unroll
    for (int j = 0; j < KP1; ++j) m[j] = 1e30f;
#pragma unroll 4
    for (int ch = 0; ch < NCHUNK; ++ch) {
#pragma unroll
        for (int j = 0; j < KP1; ++j) {
            float d2 = part[(size_t)(ch * KP1 + j) * NN + row];
#pragma unroll
            for (int jj = KP1 - 1; jj >= 1; --jj)
                m[jj] = __builtin_amdgcn_fmed3f(d2, m[jj - 1], m[jj]);
            m[0] = fminf(d2, m[0]);
        }
    }
    const float sqq = sqb[row];
    float sum = 0.f;
#pragma unroll
    for (int j = 1; j < KP1; ++j)
        sum += sqrtf(fmaxf(m[j] + sqq, 1e-12f));
    sumk[row] = sum;

    float p = sum;
#pragma unroll
    for (int off = 32; off >= 1; off >>= 1) p += __shfl_xor(p, off, 64);
    __shared__ float red[4];
    if ((threadIdx.x & 63) == 0) red[threadIdx.x >> 6] = p;
    __syncthreads();
    if (threadIdx.x == 0) psum[blockIdx.x] = red[0] + red[1] + red[2] + red[3];
}

// ---------------- Kernel 4: mean over 32 partials -> q = EPS * mean^2
__global__ void reduce_kernel(const float* __restrict__ psum, float* __restrict__ qv)
{
    const int t = threadIdx.x;
    float p = (t < 32) ? psum[t] : 0.f;
#pragma unroll
    for (int off = 32; off >= 1; off >>= 1) p += __shfl_xor(p, off, 64);
    if (t == 0) {
        float mean = p * (1.0f / NN);
        qv[0] = EPSF * mean * mean;
    }
}

// ---------------- Kernel 5: out = q / (s^2 + q)
__global__ __launch_bounds__(256) void final_kernel(
    const float* __restrict__ sumk, const float* __restrict__ qv,
    float* __restrict__ out)
{
    const int i = blockIdx.x * 256 + threadIdx.x;
    const float qq = qv[0];
    const float sv = sumk[i];
    out[i] = qq / (fmaf(sv, sv, qq));
}

extern "C" void kernel_launch(void* const* d_in, const int* in_sizes, int n_in,
                              void* d_out, int out_size, void* d_ws, size_t ws_size,
                              hipStream_t stream)
{
    const float* s  = (const float*)d_in[0];
    const float* W1 = (const float*)d_in[1];
    const float* b1 = (const float*)d_in[2];
    const float* W2 = (const float*)d_in[3];
    const float* b2 = (const float*)d_in[4];
    float* out = (float*)d_out;

    char* ws = (char*)d_ws;
    __hip_bfloat16* xb  = (__hip_bfloat16*)ws;                      // 2 MB
    __hip_bfloat16* xb2 = xb + (size_t)NN * DE;                     // 2 MB
    float* sqb  = (float*)(ws + (size_t)2 * NN * DE * 2);           // 32 KB
    float* part = sqb + NN;                                         // 32*11*8192*4 = 11.3 MB
    float* sumk = part + (size_t)NCHUNK * KP1 * NN;                 // 32 KB
    float* psum = sumk + NN;                                        // 128 B
    float* qv   = psum + 32;                                        // 4 B
    ushort* W1h = (ushort*)(qv + 1);                                // 128 KB
    ushort* W1l = W1h + (size_t)HID * SD;                           // 128 KB
    ushort* W2h = W1l + (size_t)HID * SD;                           // 32 KB
    ushort* W2l = W2h + (size_t)DE * HID;                           // 32 KB

    wsplit_kernel<<<80, 256, 0, stream>>>(W1, W2, W1h, W1l, W2h, W2l);
    mlp_kernel<<<NN / 32, 256, 0, stream>>>(s, W1h, W1l, b1, W2h, W2l, b2, xb, xb2, sqb);
    knn_kernel<<<(NN / 128) * NSPLIT, 256, 0, stream>>>(
        (const ushort*)xb, (const ushort*)xb2, sqb, part);
    merge_kernel<<<NN / 256, 256, 0, stream>>>(part, sqb, sumk, psum);
    reduce_kernel<<<1, 64, 0, stream>>>(psum, qv);
    final_kernel<<<NN / 256, 256, 0, stream>>>(sumk, qv, out);
}

// Round 7
// 107.733 us; speedup vs baseline: 1.0357x; 1.0357x over previous
//
#include <hip/hip_runtime.h>
#include <hip/hip_bf16.h>

#define NN 8192
#define SD 512
#define HID 128
#define DE 128
#define KP1 11
#define EPSF 0.001f
#define NSPLIT 32
#define NCHUNK NSPLIT        // 32 partial lists per row
#define TILE 32
#define NTILE ((NN / NSPLIT) / TILE)   // 8 tiles of 32 candidates per block

using short8 = __attribute__((ext_vector_type(8))) short;
using f32x4 = __attribute__((ext_vector_type(4))) float;

__device__ inline ushort f2bf(float f) {
    __hip_bfloat16 b = __float2bfloat16(f);
    return *reinterpret_cast<ushort*>(&b);
}
__device__ inline float bf2f(ushort u) {
    unsigned v = (unsigned)u << 16;
    union { unsigned u; float f; } c; c.u = v; return c.f;
}

// ---------------- Kernel 0: pre-split W1, W2 into hi/lo bf16 (layout unchanged: [col][k])
__global__ __launch_bounds__(256) void wsplit_kernel(
    const float* __restrict__ W1, const float* __restrict__ W2,
    ushort* __restrict__ W1h, ushort* __restrict__ W1l,
    ushort* __restrict__ W2h, ushort* __restrict__ W2l)
{
    const int bid = blockIdx.x;
    const float* src; ushort *dh, *dl; int base;
    if (bid < 64) { src = W1; dh = W1h; dl = W1l; base = bid * 1024; }
    else          { src = W2; dh = W2h; dl = W2l; base = (bid - 64) * 1024; }
    const int i = base + threadIdx.x * 4;
    float4 f = *reinterpret_cast<const float4*>(src + i);
    ushort h[4], lo[4];
    float fv[4] = {f.x, f.y, f.z, f.w};
#pragma unroll
    for (int j = 0; j < 4; ++j) {
        h[j] = f2bf(fv[j]);
        lo[j] = f2bf(fv[j] - bf2f(h[j]));
    }
    *reinterpret_cast<uint2*>(dh + i) = *reinterpret_cast<uint2*>(h);
    *reinterpret_cast<uint2*>(dl + i) = *reinterpret_cast<uint2*>(lo);
}

// ---------------- Kernel 1: split-bf16 MFMA MLP. Block = 32 rows x 128 cols, 4 waves.
// Outputs: xb = bf16(x), sqb = ||bf16(x)||^2
__global__ __launch_bounds__(256) void mlp_kernel(
    const float* __restrict__ s, const ushort* __restrict__ W1h,
    const ushort* __restrict__ W1l, const float* __restrict__ b1,
    const ushort* __restrict__ W2h, const ushort* __restrict__ W2l,
    const float* __restrict__ b2, __hip_bfloat16* __restrict__ xb,
    float* __restrict__ sqb)
{
    __shared__ __align__(16) ushort sbh[2][32 * 32];
    __shared__ __align__(16) ushort sbl[2][32 * 32];
    __shared__ __align__(16) ushort hbh[32 * 128];
    __shared__ __align__(16) ushort hbl[32 * 128];
    __shared__ __align__(16) ushort xtile[32 * 128];
    __shared__ float sqpart[4 * 32];

    const int t = threadIdx.x;
    const int w = t >> 6, l = t & 63;
    const int lc = l & 15, c4 = l >> 4;
    const int rb = blockIdx.x * 32;
    const int cb = w * 32;

    const int srow = t >> 3, skq = t & 7;
    const int ssl = ((skq >> 1) + (srow >> 2)) & 3;
    const int sByte = srow * 64 + (ssl ^ (srow & 3)) * 16 + (skq & 1) * 8;
    const float* sgbase = s + (size_t)(rb + srow) * SD + skq * 4;

    float4 sf;
#define STAGE_LOAD_S(kt_) sf = *reinterpret_cast<const float4*>(sgbase + (kt_) * 32)
#define STAGE_WRITE_S(b_) do { \
    float fv_[4] = {sf.x, sf.y, sf.z, sf.w}; \
    ushort h_[4], lo_[4]; \
    _Pragma("unroll") \
    for (int j_ = 0; j_ < 4; ++j_) { \
        h_[j_] = f2bf(fv_[j_]); \
        lo_[j_] = f2bf(fv_[j_] - bf2f(h_[j_])); \
    } \
    *reinterpret_cast<uint2*>(reinterpret_cast<char*>(sbh[b_]) + sByte) = *reinterpret_cast<uint2*>(h_); \
    *reinterpret_cast<uint2*>(reinterpret_cast<char*>(sbl[b_]) + sByte) = *reinterpret_cast<uint2*>(lo_); \
} while (0)

    int aByte[2];
#pragma unroll
    for (int rt = 0; rt < 2; ++rt) {
        int row = rt * 16 + lc;
        int sl = ((c4 + (row >> 2)) & 3) ^ (row & 3);
        aByte[rt] = row * 64 + sl * 16;
    }

    const ushort* w1hp[2]; const ushort* w1lp[2];
#pragma unroll
    for (int ct = 0; ct < 2; ++ct) {
        int col = cb + ct * 16 + lc;
        w1hp[ct] = W1h + (size_t)col * SD + c4 * 8;
        w1lp[ct] = W1l + (size_t)col * SD + c4 * 8;
    }

    f32x4 acc1[2][2];
#pragma unroll
    for (int rt = 0; rt < 2; ++rt)
#pragma unroll
        for (int ct = 0; ct < 2; ++ct) acc1[rt][ct] = {0.f, 0.f, 0.f, 0.f};

    STAGE_LOAD_S(0);
    STAGE_WRITE_S(0);
    short8 bh[2], bl[2], nbh[2], nbl[2];
#pragma unroll
    for (int ct = 0; ct < 2; ++ct) {
        bh[ct] = *reinterpret_cast<const short8*>(w1hp[ct]);
        bl[ct] = *reinterpret_cast<const short8*>(w1lp[ct]);
    }

    for (int kt = 0; kt < 16; ++kt) {
        __syncthreads();
        if (kt < 15) STAGE_LOAD_S(kt + 1);
        short8 ah[2], al[2];
#pragma unroll
        for (int rt = 0; rt < 2; ++rt) {
            ah[rt] = *reinterpret_cast<const short8*>(
                reinterpret_cast<char*>(sbh[kt & 1]) + aByte[rt]);
            al[rt] = *reinterpret_cast<const short8*>(
                reinterpret_cast<char*>(sbl[kt & 1]) + aByte[rt]);
        }
        if (kt < 15) {
#pragma unroll
            for (int ct = 0; ct < 2; ++ct) {
                nbh[ct] = *reinterpret_cast<const short8*>(w1hp[ct] + (kt + 1) * 32);
                nbl[ct] = *reinterpret_cast<const short8*>(w1lp[ct] + (kt + 1) * 32);
            }
        }
#pragma unroll
        for (int rt = 0; rt < 2; ++rt)
#pragma unroll
            for (int ct = 0; ct < 2; ++ct) {
                acc1[rt][ct] = __builtin_amdgcn_mfma_f32_16x16x32_bf16(ah[rt], bh[ct], acc1[rt][ct], 0, 0, 0);
                acc1[rt][ct] = __builtin_amdgcn_mfma_f32_16x16x32_bf16(ah[rt], bl[ct], acc1[rt][ct], 0, 0, 0);
                acc1[rt][ct] = __builtin_amdgcn_mfma_f32_16x16x32_bf16(al[rt], bh[ct], acc1[rt][ct], 0, 0, 0);
            }
        if (kt < 15) {
            STAGE_WRITE_S((kt + 1) & 1);
#pragma unroll
            for (int ct = 0; ct < 2; ++ct) { bh[ct] = nbh[ct]; bl[ct] = nbl[ct]; }
        }
    }

    float b1v[2];
#pragma unroll
    for (int ct = 0; ct < 2; ++ct) b1v[ct] = b1[cb + ct * 16 + lc];
#pragma unroll
    for (int rt = 0; rt < 2; ++rt)
#pragma unroll
        for (int ct = 0; ct < 2; ++ct)
#pragma unroll
            for (int reg = 0; reg < 4; ++reg) {
                float v = fmaxf(acc1[rt][ct][reg] + b1v[ct], 0.f);
                ushort hh = f2bf(v);
                ushort hl = f2bf(v - bf2f(hh));
                int row = rt * 16 + c4 * 4 + reg;
                int kcol = cb + ct * 16 + lc;
                int sl = (kcol >> 3) ^ (row & 15);
                int byte = row * 256 + sl * 16 + (kcol & 7) * 2;
                *reinterpret_cast<ushort*>(reinterpret_cast<char*>(hbh) + byte) = hh;
                *reinterpret_cast<ushort*>(reinterpret_cast<char*>(hbl) + byte) = hl;
            }
    __syncthreads();

    f32x4 acc2[2][2];
#pragma unroll
    for (int rt = 0; rt < 2; ++rt)
#pragma unroll
        for (int ct = 0; ct < 2; ++ct) acc2[rt][ct] = {0.f, 0.f, 0.f, 0.f};

#pragma unroll
    for (int kt = 0; kt < 4; ++kt) {
        short8 ah[2], al[2];
#pragma unroll
        for (int rt = 0; rt < 2; ++rt) {
            int row = rt * 16 + lc;
            int sl = (kt * 4 + c4) ^ (row & 15);
            int byte = row * 256 + sl * 16;
            ah[rt] = *reinterpret_cast<const short8*>(reinterpret_cast<char*>(hbh) + byte);
            al[rt] = *reinterpret_cast<const short8*>(reinterpret_cast<char*>(hbl) + byte);
        }
        short8 wh[2], wl[2];
#pragma unroll
        for (int ct = 0; ct < 2; ++ct) {
            int col = cb + ct * 16 + lc;
            wh[ct] = *reinterpret_cast<const short8*>(W2h + (size_t)col * HID + kt * 32 + c4 * 8);
            wl[ct] = *reinterpret_cast<const short8*>(W2l + (size_t)col * HID + kt * 32 + c4 * 8);
        }
#pragma unroll
        for (int rt = 0; rt < 2; ++rt)
#pragma unroll
            for (int ct = 0; ct < 2; ++ct) {
                acc2[rt][ct] = __builtin_amdgcn_mfma_f32_16x16x32_bf16(ah[rt], wh[ct], acc2[rt][ct], 0, 0, 0);
                acc2[rt][ct] = __builtin_amdgcn_mfma_f32_16x16x32_bf16(ah[rt], wl[ct], acc2[rt][ct], 0, 0, 0);
                acc2[rt][ct] = __builtin_amdgcn_mfma_f32_16x16x32_bf16(al[rt], wh[ct], acc2[rt][ct], 0, 0, 0);
            }
    }

    float b2v[2];
#pragma unroll
    for (int ct = 0; ct < 2; ++ct) b2v[ct] = b2[cb + ct * 16 + lc];
    float p[8];
#pragma unroll
    for (int j = 0; j < 8; ++j) p[j] = 0.f;
#pragma unroll
    for (int rt = 0; rt < 2; ++rt)
#pragma unroll
        for (int ct = 0; ct < 2; ++ct)
#pragma unroll
            for (int reg = 0; reg < 4; ++reg) {
                float v = acc2[rt][ct][reg] + b2v[ct];
                ushort xv = f2bf(v);
                float xf = bf2f(xv);
                p[rt * 4 + reg] = fmaf(xf, xf, p[rt * 4 + reg]);
                int row = rt * 16 + c4 * 4 + reg;
                int e = cb + ct * 16 + lc;
                xtile[row * 128 + e] = xv;
            }
#pragma unroll
    for (int j = 0; j < 8; ++j) {
#pragma unroll
        for (int off = 8; off >= 1; off >>= 1) p[j] += __shfl_xor(p[j], off, 16);
    }
    if (lc == 0) {
#pragma unroll
        for (int rt = 0; rt < 2; ++rt)
#pragma unroll
            for (int reg = 0; reg < 4; ++reg)
                sqpart[w * 32 + rt * 16 + c4 * 4 + reg] = p[rt * 4 + reg];
    }
    __syncthreads();
    if (t < 32)
        sqb[rb + t] = sqpart[t] + sqpart[32 + t] + sqpart[64 + t] + sqpart[96 + t];
    const short8* xsv = reinterpret_cast<const short8*>(xtile);
    short8* xg = reinterpret_cast<short8*>(reinterpret_cast<ushort*>(xb) + (size_t)rb * DE);
    xg[t] = xsv[t];
    xg[t + 256] = xsv[t + 256];
}

// ---------------- Kernel 2: per-row top-11 of d2'' = sq[c]/2 - x_q.x_c, via MFMA with
// B = NEGATED query frags (in-register sign flip, exact), C-in = 0.5*sq[c] (exact).
// Single x array -> 2MB L2-resident hot set. 32 queries/wave, 32-cand dbuf LDS tiles.
__global__ __launch_bounds__(256, 6) void knn_kernel(
    const ushort* __restrict__ xs, const float* __restrict__ sqb,
    float* __restrict__ part)
{
    __shared__ __align__(16) ushort lbuf[2][TILE * DE];   // 2 x 8KB (merge buffer overlays)
    __shared__ __align__(16) float sqs[NN / NSPLIT];      // 1KB

    const int bid = blockIdx.x;              // 2048 = 64 row-groups x 32 cand-splits
    const int rid = bid >> 5, cid = bid & 31;
    const int t = threadIdx.x;
    const int w = t >> 6, l = t & 63;
    const int q16 = l & 15, lg = l >> 4;
    const int kk = lg * 8;
    const int qb = rid * 128 + w * 32;
    const int cstart = cid * (NN / NSPLIT);  // 256 candidates per block

    // B-frags: NEGATED queries (sign-bit XOR on packed bf16 pairs; exact, -0 -> +0 ok)
    short8 bq[2][4];
#pragma unroll
    for (int qs = 0; qs < 2; ++qs)
#pragma unroll
        for (int kb = 0; kb < 4; ++kb) {
            bq[qs][kb] = *reinterpret_cast<const short8*>(
                xs + (size_t)(qb + qs * 16 + q16) * DE + kb * 32 + kk);
            unsigned* u = reinterpret_cast<unsigned*>(&bq[qs][kb]);
#pragma unroll
            for (int i = 0; i < 4; ++i) u[i] ^= 0x80008000u;
        }

    float m[2][KP1];
#pragma unroll
    for (int qs = 0; qs < 2; ++qs)
#pragma unroll
        for (int j = 0; j < KP1; ++j) m[qs][j] = 1e30f;

#define INS(qs_, v_) do { \
    float d2_ = (v_); \
    _Pragma("unroll") \
    for (int j_ = KP1 - 1; j_ >= 1; --j_) \
        m[qs_][j_] = __builtin_amdgcn_fmed3f(d2_, m[qs_][j_ - 1], m[qs_][j_]); \
    m[qs_][0] = fminf(d2_, m[qs_][0]); \
} while (0)

    // stage 0.5*sq for the block's candidate range once (exact exponent shift)
    if (t < 64) {
        float4 v = reinterpret_cast<const float4*>(sqb + cstart)[t];
        v.x *= 0.5f; v.y *= 0.5f; v.z *= 0.5f; v.w *= 0.5f;
        reinterpret_cast<float4*>(sqs)[t] = v;
    }

    // staging: thread t owns 2 16B slots s = t, t+256 of the 512-slot (8KB) tile
    int gIdx[2], dIdx[2];
#pragma unroll
    for (int i = 0; i < 2; ++i) {
        int sl = t + 256 * i;
        int row = sl >> 4, col = sl & 15;
        gIdx[i] = row * DE + col * 8;                       // ushort units
        dIdx[i] = (row * 16 + (col ^ (row & 7))) * 8;
    }
    // A-frag base indices (row = q16 within a 16-cand subtile)
    int aIdx[4];
#pragma unroll
    for (int kb = 0; kb < 4; ++kb)
        aIdx[kb] = (q16 * 16 + ((kb * 4 + lg) ^ (q16 & 7))) * 8;

    short8 st[2];
#define STAGE_LOAD(tt_) do { \
    const ushort* sb_ = xs + (size_t)(cstart + (tt_) * TILE) * DE; \
    st[0] = *reinterpret_cast<const short8*>(sb_ + gIdx[0]); \
    st[1] = *reinterpret_cast<const short8*>(sb_ + gIdx[1]); \
} while (0)
#define STAGE_WRITE(nb_) do { \
    *reinterpret_cast<short8*>(&lbuf[nb_][dIdx[0]]) = st[0]; \
    *reinterpret_cast<short8*>(&lbuf[nb_][dIdx[1]]) = st[1]; \
} while (0)

    STAGE_LOAD(0);
    STAGE_WRITE(0);

    for (int tt = 0; tt < NTILE; ++tt) {
        __syncthreads();                     // publishes lbuf[tt&1] (and sqs on tt=0)
        if (tt + 1 < NTILE) STAGE_LOAD(tt + 1);
        const ushort* lb = lbuf[tt & 1];
#pragma unroll
        for (int cs = 0; cs < 2; ++cs) {     // 16-cand subtiles
            short8 fa[4];
#pragma unroll
            for (int kb = 0; kb < 4; ++kb)
                fa[kb] = *reinterpret_cast<const short8*>(lb + cs * 2048 + aIdx[kb]);
            float4 sv = *reinterpret_cast<const float4*>(sqs + tt * TILE + cs * 16 + lg * 4);
#pragma unroll
            for (int qs = 0; qs < 2; ++qs) {
                f32x4 acc = {sv.x, sv.y, sv.z, sv.w};   // C-in = sq[c]/2; B = -x_q
#pragma unroll
                for (int kb = 0; kb < 4; ++kb)
                    acc = __builtin_amdgcn_mfma_f32_16x16x32_bf16(fa[kb], bq[qs][kb], acc, 0, 0, 0);
                INS(qs, acc[0]);
                INS(qs, acc[1]);
                INS(qs, acc[2]);
                INS(qs, acc[3]);
            }
        }
        if (tt + 1 < NTILE) STAGE_WRITE((tt + 1) & 1);  // buffer freed by this iter's sync
    }
#undef STAGE_LOAD
#undef STAGE_WRITE
#undef INS

    // ---- in-kernel lane-group merge, 2 phases (qs) to fit the 11KB buffer in lbuf
    float* mb = reinterpret_cast<float*>(lbuf);   // [4w][4lg][11][16] floats = 11264 B
#pragma unroll
    for (int qs = 0; qs < 2; ++qs) {
        __syncthreads();                     // lbuf free / previous phase done
#pragma unroll
        for (int j = 0; j < KP1; ++j)
            mb[((w * 4 + lg) * KP1 + j) * 16 + q16] = m[qs][j];
        __syncthreads();
        if (l < 16) {                        // lanes 0..15: q16 == l
            float mm[KP1];
#pragma unroll
            for (int j = 0; j < KP1; ++j)
                mm[j] = mb[((w * 4 + 0) * KP1 + j) * 16 + l];
#pragma unroll
            for (int g = 1; g < 4; ++g)
#pragma unroll
                for (int j = 0; j < KP1; ++j) {
                    float d2 = mb[((w * 4 + g) * KP1 + j) * 16 + l];
#pragma unroll
                    for (int jj = KP1 - 1; jj >= 1; --jj)
                        mm[jj] = __builtin_amdgcn_fmed3f(d2, mm[jj - 1], mm[jj]);
                    mm[0] = fminf(d2, mm[0]);
                }
            const int q = qb + qs * 16 + l;
#pragma unroll
            for (int j = 0; j < KP1; ++j)
                part[(size_t)(cid * KP1 + j) * NN + q] = mm[j];
        }
    }
}

// ---------------- Kernel 3: merge 32 partial top-11 lists -> sumk[row]; block partials.
// dist^2 = 2*m + sqq (m holds sq[c]/2 - dot).
__global__ __launch_bounds__(256) void merge_kernel(
    const float* __restrict__ part, const float* __restrict__ sqb,
    float* __restrict__ sumk, float* __restrict__ psum)
{
    const int row = blockIdx.x * 256 + threadIdx.x;
    float m[KP1];
#pragma unroll
    for (int j = 0; j < KP1; ++j) m[j] = 1e30f;
#pragma unroll 4
    for (int ch = 0; ch < NCHUNK; ++ch) {
#pragma unroll
        for (int j = 0; j < KP1; ++j) {
            float d2 = part[(size_t)(ch * KP1 + j) * NN + row];
#pragma unroll
            for (int jj = KP1 - 1; jj >= 1; --jj)
                m[jj] = __builtin_amdgcn_fmed3f(d2, m[jj - 1], m[jj]);
            m[0] = fminf(d2, m[0]);
        }
    }
    const float sqq = sqb[row];
    float sum = 0.f;
#pragma unroll
    for (int j = 1; j < KP1; ++j)
        sum += sqrtf(fmaxf(fmaf(2.f, m[j], sqq), 1e-12f));
    sumk[row] = sum;

    float p = sum;
#pragma unroll
    for (int off = 32; off >= 1; off >>= 1) p += __shfl_xor(p, off, 64);
    __shared__ float red[4];
    if ((threadIdx.x & 63) == 0) red[threadIdx.x >> 6] = p;
    __syncthreads();
    if (threadIdx.x == 0) psum[blockIdx.x] = red[0] + red[1] + red[2] + red[3];
}

// ---------------- Kernel 4: mean over 32 partials -> q = EPS * mean^2
__global__ void reduce_kernel(const float* __restrict__ psum, float* __restrict__ qv)
{
    const int t = threadIdx.x;
    float p = (t < 32) ? psum[t] : 0.f;
#pragma unroll
    for (int off = 32; off >= 1; off >>= 1) p += __shfl_xor(p, off, 64);
    if (t == 0) {
        float mean = p * (1.0f / NN);
        qv[0] = EPSF * mean * mean;
    }
}

// ---------------- Kernel 5: out = q / (s^2 + q)
__global__ __launch_bounds__(256) void final_kernel(
    const float* __restrict__ sumk, const float* __restrict__ qv,
    float* __restrict__ out)
{
    const int i = blockIdx.x * 256 + threadIdx.x;
    const float qq = qv[0];
    const float sv = sumk[i];
    out[i] = qq / (fmaf(sv, sv, qq));
}

extern "C" void kernel_launch(void* const* d_in, const int* in_sizes, int n_in,
                              void* d_out, int out_size, void* d_ws, size_t ws_size,
                              hipStream_t stream)
{
    const float* s  = (const float*)d_in[0];
    const float* W1 = (const float*)d_in[1];
    const float* b1 = (const float*)d_in[2];
    const float* W2 = (const float*)d_in[3];
    const float* b2 = (const float*)d_in[4];
    float* out = (float*)d_out;

    char* ws = (char*)d_ws;
    __hip_bfloat16* xb = (__hip_bfloat16*)ws;                       // 2 MB
    float* sqb  = (float*)(ws + (size_t)NN * DE * 2);               // 32 KB
    float* part = sqb + NN;                                         // 32*11*8192*4 = 11.5 MB
    float* sumk = part + (size_t)NCHUNK * KP1 * NN;                 // 32 KB
    float* psum = sumk + NN;                                        // 128 B
    float* qv   = psum + 32;                                        // 4 B
    ushort* W1h = (ushort*)(qv + 1);                                // 128 KB
    ushort* W1l = W1h + (size_t)HID * SD;                           // 128 KB
    ushort* W2h = W1l + (size_t)HID * SD;                           // 32 KB
    ushort* W2l = W2h + (size_t)DE * HID;                           // 32 KB

    wsplit_kernel<<<80, 256, 0, stream>>>(W1, W2, W1h, W1l, W2h, W2l);
    mlp_kernel<<<NN / 32, 256, 0, stream>>>(s, W1h, W1l, b1, W2h, W2l, b2, xb, sqb);
    knn_kernel<<<(NN / 128) * NSPLIT, 256, 0, stream>>>((const ushort*)xb, sqb, part);
    merge_kernel<<<NN / 256, 256, 0, stream>>>(part, sqb, sumk, psum);
    reduce_kernel<<<1, 64, 0, stream>>>(psum, qv);
    final_kernel<<<NN / 256, 256, 0, stream>>>(sumk, qv, out);
}

// Round 8
// 102.997 us; speedup vs baseline: 1.0833x; 1.0460x over previous
//
#include <hip/hip_runtime.h>
#include <hip/hip_bf16.h>

#define NN 8192
#define SD 512
#define HID 128
#define DE 128
#define KP1 11
#define EPSF 0.001f
#define NSPLIT 32
#define NCHUNK NSPLIT        // 32 partial lists per row
#define TILE 32
#define NTILE ((NN / NSPLIT) / TILE)   // 8 tiles of 32 candidates per block
#define PBLK (4 * 2 * KP1 * 16)        // 1408 floats = 5632 B per block, contiguous

using short8 = __attribute__((ext_vector_type(8))) short;
using f32x4 = __attribute__((ext_vector_type(4))) float;

__device__ inline ushort f2bf(float f) {
    __hip_bfloat16 b = __float2bfloat16(f);
    return *reinterpret_cast<ushort*>(&b);
}
__device__ inline float bf2f(ushort u) {
    unsigned v = (unsigned)u << 16;
    union { unsigned u; float f; } c; c.u = v; return c.f;
}

// ---------------- Kernel 0: pre-split W1, W2 into hi/lo bf16 (layout unchanged: [col][k])
__global__ __launch_bounds__(256) void wsplit_kernel(
    const float* __restrict__ W1, const float* __restrict__ W2,
    ushort* __restrict__ W1h, ushort* __restrict__ W1l,
    ushort* __restrict__ W2h, ushort* __restrict__ W2l)
{
    const int bid = blockIdx.x;
    const float* src; ushort *dh, *dl; int base;
    if (bid < 64) { src = W1; dh = W1h; dl = W1l; base = bid * 1024; }
    else          { src = W2; dh = W2h; dl = W2l; base = (bid - 64) * 1024; }
    const int i = base + threadIdx.x * 4;
    float4 f = *reinterpret_cast<const float4*>(src + i);
    ushort h[4], lo[4];
    float fv[4] = {f.x, f.y, f.z, f.w};
#pragma unroll
    for (int j = 0; j < 4; ++j) {
        h[j] = f2bf(fv[j]);
        lo[j] = f2bf(fv[j] - bf2f(h[j]));
    }
    *reinterpret_cast<uint2*>(dh + i) = *reinterpret_cast<uint2*>(h);
    *reinterpret_cast<uint2*>(dl + i) = *reinterpret_cast<uint2*>(lo);
}

// ---------------- Kernel 1: split-bf16 MFMA MLP. Block = 32 rows x 128 cols, 4 waves.
// Outputs: xb = bf16(x), sqb = ||bf16(x)||^2
__global__ __launch_bounds__(256) void mlp_kernel(
    const float* __restrict__ s, const ushort* __restrict__ W1h,
    const ushort* __restrict__ W1l, const float* __restrict__ b1,
    const ushort* __restrict__ W2h, const ushort* __restrict__ W2l,
    const float* __restrict__ b2, __hip_bfloat16* __restrict__ xb,
    float* __restrict__ sqb)
{
    __shared__ __align__(16) ushort sbh[2][32 * 32];
    __shared__ __align__(16) ushort sbl[2][32 * 32];
    __shared__ __align__(16) ushort hbh[32 * 128];
    __shared__ __align__(16) ushort hbl[32 * 128];
    __shared__ __align__(16) ushort xtile[32 * 128];
    __shared__ float sqpart[4 * 32];

    const int t = threadIdx.x;
    const int w = t >> 6, l = t & 63;
    const int lc = l & 15, c4 = l >> 4;
    const int rb = blockIdx.x * 32;
    const int cb = w * 32;

    const int srow = t >> 3, skq = t & 7;
    const int ssl = ((skq >> 1) + (srow >> 2)) & 3;
    const int sByte = srow * 64 + (ssl ^ (srow & 3)) * 16 + (skq & 1) * 8;
    const float* sgbase = s + (size_t)(rb + srow) * SD + skq * 4;

    float4 sf;
#define STAGE_LOAD_S(kt_) sf = *reinterpret_cast<const float4*>(sgbase + (kt_) * 32)
#define STAGE_WRITE_S(b_) do { \
    float fv_[4] = {sf.x, sf.y, sf.z, sf.w}; \
    ushort h_[4], lo_[4]; \
    _Pragma("unroll") \
    for (int j_ = 0; j_ < 4; ++j_) { \
        h_[j_] = f2bf(fv_[j_]); \
        lo_[j_] = f2bf(fv_[j_] - bf2f(h_[j_])); \
    } \
    *reinterpret_cast<uint2*>(reinterpret_cast<char*>(sbh[b_]) + sByte) = *reinterpret_cast<uint2*>(h_); \
    *reinterpret_cast<uint2*>(reinterpret_cast<char*>(sbl[b_]) + sByte) = *reinterpret_cast<uint2*>(lo_); \
} while (0)

    int aByte[2];
#pragma unroll
    for (int rt = 0; rt < 2; ++rt) {
        int row = rt * 16 + lc;
        int sl = ((c4 + (row >> 2)) & 3) ^ (row & 3);
        aByte[rt] = row * 64 + sl * 16;
    }

    const ushort* w1hp[2]; const ushort* w1lp[2];
#pragma unroll
    for (int ct = 0; ct < 2; ++ct) {
        int col = cb + ct * 16 + lc;
        w1hp[ct] = W1h + (size_t)col * SD + c4 * 8;
        w1lp[ct] = W1l + (size_t)col * SD + c4 * 8;
    }

    f32x4 acc1[2][2];
#pragma unroll
    for (int rt = 0; rt < 2; ++rt)
#pragma unroll
        for (int ct = 0; ct < 2; ++ct) acc1[rt][ct] = {0.f, 0.f, 0.f, 0.f};

    STAGE_LOAD_S(0);
    STAGE_WRITE_S(0);
    short8 bh[2], bl[2], nbh[2], nbl[2];
#pragma unroll
    for (int ct = 0; ct < 2; ++ct) {
        bh[ct] = *reinterpret_cast<const short8*>(w1hp[ct]);
        bl[ct] = *reinterpret_cast<const short8*>(w1lp[ct]);
    }

    for (int kt = 0; kt < 16; ++kt) {
        __syncthreads();
        if (kt < 15) STAGE_LOAD_S(kt + 1);
        short8 ah[2], al[2];
#pragma unroll
        for (int rt = 0; rt < 2; ++rt) {
            ah[rt] = *reinterpret_cast<const short8*>(
                reinterpret_cast<char*>(sbh[kt & 1]) + aByte[rt]);
            al[rt] = *reinterpret_cast<const short8*>(
                reinterpret_cast<char*>(sbl[kt & 1]) + aByte[rt]);
        }
        if (kt < 15) {
#pragma unroll
            for (int ct = 0; ct < 2; ++ct) {
                nbh[ct] = *reinterpret_cast<const short8*>(w1hp[ct] + (kt + 1) * 32);
                nbl[ct] = *reinterpret_cast<const short8*>(w1lp[ct] + (kt + 1) * 32);
            }
        }
#pragma unroll
        for (int rt = 0; rt < 2; ++rt)
#pragma unroll
            for (int ct = 0; ct < 2; ++ct) {
                acc1[rt][ct] = __builtin_amdgcn_mfma_f32_16x16x32_bf16(ah[rt], bh[ct], acc1[rt][ct], 0, 0, 0);
                acc1[rt][ct] = __builtin_amdgcn_mfma_f32_16x16x32_bf16(ah[rt], bl[ct], acc1[rt][ct], 0, 0, 0);
                acc1[rt][ct] = __builtin_amdgcn_mfma_f32_16x16x32_bf16(al[rt], bh[ct], acc1[rt][ct], 0, 0, 0);
            }
        if (kt < 15) {
            STAGE_WRITE_S((kt + 1) & 1);
#pragma unroll
            for (int ct = 0; ct < 2; ++ct) { bh[ct] = nbh[ct]; bl[ct] = nbl[ct]; }
        }
    }

    float b1v[2];
#pragma unroll
    for (int ct = 0; ct < 2; ++ct) b1v[ct] = b1[cb + ct * 16 + lc];
#pragma unroll
    for (int rt = 0; rt < 2; ++rt)
#pragma unroll
        for (int ct = 0; ct < 2; ++ct)
#pragma unroll
            for (int reg = 0; reg < 4; ++reg) {
                float v = fmaxf(acc1[rt][ct][reg] + b1v[ct], 0.f);
                ushort hh = f2bf(v);
                ushort hl = f2bf(v - bf2f(hh));
                int row = rt * 16 + c4 * 4 + reg;
                int kcol = cb + ct * 16 + lc;
                int sl = (kcol >> 3) ^ (row & 15);
                int byte = row * 256 + sl * 16 + (kcol & 7) * 2;
                *reinterpret_cast<ushort*>(reinterpret_cast<char*>(hbh) + byte) = hh;
                *reinterpret_cast<ushort*>(reinterpret_cast<char*>(hbl) + byte) = hl;
            }
    __syncthreads();

    f32x4 acc2[2][2];
#pragma unroll
    for (int rt = 0; rt < 2; ++rt)
#pragma unroll
        for (int ct = 0; ct < 2; ++ct) acc2[rt][ct] = {0.f, 0.f, 0.f, 0.f};

#pragma unroll
    for (int kt = 0; kt < 4; ++kt) {
        short8 ah[2], al[2];
#pragma unroll
        for (int rt = 0; rt < 2; ++rt) {
            int row = rt * 16 + lc;
            int sl = (kt * 4 + c4) ^ (row & 15);
            int byte = row * 256 + sl * 16;
            ah[rt] = *reinterpret_cast<const short8*>(reinterpret_cast<char*>(hbh) + byte);
            al[rt] = *reinterpret_cast<const short8*>(reinterpret_cast<char*>(hbl) + byte);
        }
        short8 wh[2], wl[2];
#pragma unroll
        for (int ct = 0; ct < 2; ++ct) {
            int col = cb + ct * 16 + lc;
            wh[ct] = *reinterpret_cast<const short8*>(W2h + (size_t)col * HID + kt * 32 + c4 * 8);
            wl[ct] = *reinterpret_cast<const short8*>(W2l + (size_t)col * HID + kt * 32 + c4 * 8);
        }
#pragma unroll
        for (int rt = 0; rt < 2; ++rt)
#pragma unroll
            for (int ct = 0; ct < 2; ++ct) {
                acc2[rt][ct] = __builtin_amdgcn_mfma_f32_16x16x32_bf16(ah[rt], wh[ct], acc2[rt][ct], 0, 0, 0);
                acc2[rt][ct] = __builtin_amdgcn_mfma_f32_16x16x32_bf16(ah[rt], wl[ct], acc2[rt][ct], 0, 0, 0);
                acc2[rt][ct] = __builtin_amdgcn_mfma_f32_16x16x32_bf16(al[rt], wh[ct], acc2[rt][ct], 0, 0, 0);
            }
    }

    float b2v[2];
#pragma unroll
    for (int ct = 0; ct < 2; ++ct) b2v[ct] = b2[cb + ct * 16 + lc];
    float p[8];
#pragma unroll
    for (int j = 0; j < 8; ++j) p[j] = 0.f;
#pragma unroll
    for (int rt = 0; rt < 2; ++rt)
#pragma unroll
        for (int ct = 0; ct < 2; ++ct)
#pragma unroll
            for (int reg = 0; reg < 4; ++reg) {
                float v = acc2[rt][ct][reg] + b2v[ct];
                ushort xv = f2bf(v);
                float xf = bf2f(xv);
                p[rt * 4 + reg] = fmaf(xf, xf, p[rt * 4 + reg]);
                int row = rt * 16 + c4 * 4 + reg;
                int e = cb + ct * 16 + lc;
                xtile[row * 128 + e] = xv;
            }
#pragma unroll
    for (int j = 0; j < 8; ++j) {
#pragma unroll
        for (int off = 8; off >= 1; off >>= 1) p[j] += __shfl_xor(p[j], off, 16);
    }
    if (lc == 0) {
#pragma unroll
        for (int rt = 0; rt < 2; ++rt)
#pragma unroll
            for (int reg = 0; reg < 4; ++reg)
                sqpart[w * 32 + rt * 16 + c4 * 4 + reg] = p[rt * 4 + reg];
    }
    __syncthreads();
    if (t < 32)
        sqb[rb + t] = sqpart[t] + sqpart[32 + t] + sqpart[64 + t] + sqpart[96 + t];
    const short8* xsv = reinterpret_cast<const short8*>(xtile);
    short8* xg = reinterpret_cast<short8*>(reinterpret_cast<ushort*>(xb) + (size_t)rb * DE);
    xg[t] = xsv[t];
    xg[t + 256] = xsv[t + 256];
}

// ---------------- Kernel 2: per-row top-11 of d2'' = sq[c]/2 - x_q.x_c, via MFMA with
// B = NEGATED query frags, C-in = 0.5*sq[c]. Block-CONTIGUOUS part writes (no RMW).
__global__ __launch_bounds__(256, 6) void knn_kernel(
    const ushort* __restrict__ xs, const float* __restrict__ sqb,
    float* __restrict__ part)
{
    __shared__ __align__(16) ushort lbuf[2][TILE * DE];   // 2 x 8KB (merge buffer overlays)
    __shared__ __align__(16) float sqs[NN / NSPLIT];      // 1KB

    const int bid = blockIdx.x;              // 2048 = 64 row-groups x 32 cand-splits
    const int rid = bid >> 5, cid = bid & 31;
    const int t = threadIdx.x;
    const int w = t >> 6, l = t & 63;
    const int q16 = l & 15, lg = l >> 4;
    const int kk = lg * 8;
    const int qb = rid * 128 + w * 32;
    const int cstart = cid * (NN / NSPLIT);  // 256 candidates per block

    // B-frags: NEGATED queries (sign-bit XOR on packed bf16 pairs; exact)
    short8 bq[2][4];
#pragma unroll
    for (int qs = 0; qs < 2; ++qs)
#pragma unroll
        for (int kb = 0; kb < 4; ++kb) {
            bq[qs][kb] = *reinterpret_cast<const short8*>(
                xs + (size_t)(qb + qs * 16 + q16) * DE + kb * 32 + kk);
            unsigned* u = reinterpret_cast<unsigned*>(&bq[qs][kb]);
#pragma unroll
            for (int i = 0; i < 4; ++i) u[i] ^= 0x80008000u;
        }

    float m[2][KP1];
#pragma unroll
    for (int qs = 0; qs < 2; ++qs)
#pragma unroll
        for (int j = 0; j < KP1; ++j) m[qs][j] = 1e30f;

#define INS(qs_, v_) do { \
    float d2_ = (v_); \
    _Pragma("unroll") \
    for (int j_ = KP1 - 1; j_ >= 1; --j_) \
        m[qs_][j_] = __builtin_amdgcn_fmed3f(d2_, m[qs_][j_ - 1], m[qs_][j_]); \
    m[qs_][0] = fminf(d2_, m[qs_][0]); \
} while (0)

    // stage 0.5*sq for the block's candidate range once (exact exponent shift)
    if (t < 64) {
        float4 v = reinterpret_cast<const float4*>(sqb + cstart)[t];
        v.x *= 0.5f; v.y *= 0.5f; v.z *= 0.5f; v.w *= 0.5f;
        reinterpret_cast<float4*>(sqs)[t] = v;
    }

    // staging: thread t owns 2 16B slots s = t, t+256 of the 512-slot (8KB) tile
    int gIdx[2], dIdx[2];
#pragma unroll
    for (int i = 0; i < 2; ++i) {
        int sl = t + 256 * i;
        int row = sl >> 4, col = sl & 15;
        gIdx[i] = row * DE + col * 8;                       // ushort units
        dIdx[i] = (row * 16 + (col ^ (row & 7))) * 8;
    }
    // A-frag base indices (row = q16 within a 16-cand subtile)
    int aIdx[4];
#pragma unroll
    for (int kb = 0; kb < 4; ++kb)
        aIdx[kb] = (q16 * 16 + ((kb * 4 + lg) ^ (q16 & 7))) * 8;

    short8 st[2];
#define STAGE_LOAD(tt_) do { \
    const ushort* sb_ = xs + (size_t)(cstart + (tt_) * TILE) * DE; \
    st[0] = *reinterpret_cast<const short8*>(sb_ + gIdx[0]); \
    st[1] = *reinterpret_cast<const short8*>(sb_ + gIdx[1]); \
} while (0)
#define STAGE_WRITE(nb_) do { \
    *reinterpret_cast<short8*>(&lbuf[nb_][dIdx[0]]) = st[0]; \
    *reinterpret_cast<short8*>(&lbuf[nb_][dIdx[1]]) = st[1]; \
} while (0)

    STAGE_LOAD(0);
    STAGE_WRITE(0);

    for (int tt = 0; tt < NTILE; ++tt) {
        __syncthreads();                     // publishes lbuf[tt&1] (and sqs on tt=0)
        if (tt + 1 < NTILE) STAGE_LOAD(tt + 1);
        const ushort* lb = lbuf[tt & 1];
#pragma unroll
        for (int cs = 0; cs < 2; ++cs) {     // 16-cand subtiles
            short8 fa[4];
#pragma unroll
            for (int kb = 0; kb < 4; ++kb)
                fa[kb] = *reinterpret_cast<const short8*>(lb + cs * 2048 + aIdx[kb]);
            float4 sv = *reinterpret_cast<const float4*>(sqs + tt * TILE + cs * 16 + lg * 4);
#pragma unroll
            for (int qs = 0; qs < 2; ++qs) {
                f32x4 acc = {sv.x, sv.y, sv.z, sv.w};   // C-in = sq[c]/2; B = -x_q
#pragma unroll
                for (int kb = 0; kb < 4; ++kb)
                    acc = __builtin_amdgcn_mfma_f32_16x16x32_bf16(fa[kb], bq[qs][kb], acc, 0, 0, 0);
                INS(qs, acc[0]);
                INS(qs, acc[1]);
                INS(qs, acc[2]);
                INS(qs, acc[3]);
            }
        }
        if (tt + 1 < NTILE) STAGE_WRITE((tt + 1) & 1);  // buffer freed by this iter's sync
    }
#undef STAGE_LOAD
#undef STAGE_WRITE
#undef INS

    // ---- in-kernel lane-group merge, 2 phases (qs); block-contiguous part write:
    // part[bid][w*2+qs][j][lane16] -> 88 sequential 64B stores, 44 aligned 128B lines.
    float* mb = reinterpret_cast<float*>(lbuf);   // [4w][4lg][11][16] floats = 11264 B
    float* pout = part + (size_t)bid * PBLK;
#pragma unroll
    for (int qs = 0; qs < 2; ++qs) {
        __syncthreads();                     // lbuf free / previous phase done
#pragma unroll
        for (int j = 0; j < KP1; ++j)
            mb[((w * 4 + lg) * KP1 + j) * 16 + q16] = m[qs][j];
        __syncthreads();
        if (l < 16) {                        // lanes 0..15: q16 == l
            float mm[KP1];
#pragma unroll
            for (int j = 0; j < KP1; ++j)
                mm[j] = mb[((w * 4 + 0) * KP1 + j) * 16 + l];
#pragma unroll
            for (int g = 1; g < 4; ++g)
#pragma unroll
                for (int j = 0; j < KP1; ++j) {
                    float d2 = mb[((w * 4 + g) * KP1 + j) * 16 + l];
#pragma unroll
                    for (int jj = KP1 - 1; jj >= 1; --jj)
                        mm[jj] = __builtin_amdgcn_fmed3f(d2, mm[jj - 1], mm[jj]);
                    mm[0] = fminf(d2, mm[0]);
                }
#pragma unroll
            for (int j = 0; j < KP1; ++j)
                pout[((w * 2 + qs) * KP1 + j) * 16 + l] = mm[j];
        }
    }
}

// ---------------- Kernel 3: merge 32 partial lists (block-contiguous layout) -> sumk;
// dist^2 = 2*m + sqq (m holds sq[c]/2 - dot).
__global__ __launch_bounds__(256) void merge_kernel(
    const float* __restrict__ part, const float* __restrict__ sqb,
    float* __restrict__ sumk, float* __restrict__ psum)
{
    const int row = blockIdx.x * 256 + threadIdx.x;
    const int rid = row >> 7;
    const int sub = ((row >> 5) & 3) * 2 + ((row >> 4) & 1);   // w*2+qs
    const int lane = row & 15;
    const float* pbase = part + (size_t)rid * 32 * PBLK + sub * (KP1 * 16) + lane;

    float m[KP1];
#pragma unroll
    for (int j = 0; j < KP1; ++j) m[j] = 1e30f;
#pragma unroll 4
    for (int ch = 0; ch < NCHUNK; ++ch) {
        const float* pc = pbase + ch * PBLK;
#pragma unroll
        for (int j = 0; j < KP1; ++j) {
            float d2 = pc[j * 16];
#pragma unroll
            for (int jj = KP1 - 1; jj >= 1; --jj)
                m[jj] = __builtin_amdgcn_fmed3f(d2, m[jj - 1], m[jj]);
            m[0] = fminf(d2, m[0]);
        }
    }
    const float sqq = sqb[row];
    float sum = 0.f;
#pragma unroll
    for (int j = 1; j < KP1; ++j)
        sum += sqrtf(fmaxf(fmaf(2.f, m[j], sqq), 1e-12f));
    sumk[row] = sum;

    float p = sum;
#pragma unroll
    for (int off = 32; off >= 1; off >>= 1) p += __shfl_xor(p, off, 64);
    __shared__ float red[4];
    if ((threadIdx.x & 63) == 0) red[threadIdx.x >> 6] = p;
    __syncthreads();
    if (threadIdx.x == 0) psum[blockIdx.x] = red[0] + red[1] + red[2] + red[3];
}

// ---------------- Kernel 4: mean over 32 partials -> q = EPS * mean^2
__global__ void reduce_kernel(const float* __restrict__ psum, float* __restrict__ qv)
{
    const int t = threadIdx.x;
    float p = (t < 32) ? psum[t] : 0.f;
#pragma unroll
    for (int off = 32; off >= 1; off >>= 1) p += __shfl_xor(p, off, 64);
    if (t == 0) {
        float mean = p * (1.0f / NN);
        qv[0] = EPSF * mean * mean;
    }
}

// ---------------- Kernel 5: out = q / (s^2 + q)
__global__ __launch_bounds__(256) void final_kernel(
    const float* __restrict__ sumk, const float* __restrict__ qv,
    float* __restrict__ out)
{
    const int i = blockIdx.x * 256 + threadIdx.x;
    const float qq = qv[0];
    const float sv = sumk[i];
    out[i] = qq / (fmaf(sv, sv, qq));
}

extern "C" void kernel_launch(void* const* d_in, const int* in_sizes, int n_in,
                              void* d_out, int out_size, void* d_ws, size_t ws_size,
                              hipStream_t stream)
{
    const float* s  = (const float*)d_in[0];
    const float* W1 = (const float*)d_in[1];
    const float* b1 = (const float*)d_in[2];
    const float* W2 = (const float*)d_in[3];
    const float* b2 = (const float*)d_in[4];
    float* out = (float*)d_out;

    char* ws = (char*)d_ws;
    __hip_bfloat16* xb = (__hip_bfloat16*)ws;                       // 2 MB
    float* sqb  = (float*)(ws + (size_t)NN * DE * 2);               // 32 KB
    float* part = sqb + NN;                                         // 2048*5632B = 11.5 MB
    float* sumk = part + (size_t)2048 * PBLK;                       // 32 KB
    float* psum = sumk + NN;                                        // 128 B
    float* qv   = psum + 32;                                        // 4 B
    ushort* W1h = (ushort*)(qv + 1);                                // 128 KB
    ushort* W1l = W1h + (size_t)HID * SD;                           // 128 KB
    ushort* W2h = W1l + (size_t)HID * SD;                           // 32 KB
    ushort* W2l = W2h + (size_t)DE * HID;                           // 32 KB

    wsplit_kernel<<<80, 256, 0, stream>>>(W1, W2, W1h, W1l, W2h, W2l);
    mlp_kernel<<<NN / 32, 256, 0, stream>>>(s, W1h, W1l, b1, W2h, W2l, b2, xb, sqb);
    knn_kernel<<<(NN / 128) * NSPLIT, 256, 0, stream>>>((const ushort*)xb, sqb, part);
    merge_kernel<<<NN / 256, 256, 0, stream>>>(part, sqb, sumk, psum);
    reduce_kernel<<<1, 64, 0, stream>>>(psum, qv);
    final_kernel<<<NN / 256, 256, 0, stream>>>(sumk, qv, out);
}

// Round 9
// 78.305 us; speedup vs baseline: 1.4249x; 1.3153x over previous
//
#include <hip/hip_runtime.h>
#include <hip/hip_bf16.h>

#define NN 8192
#define SD 512
#define HID 128
#define DE 128
#define KP1 11
#define EPSF 0.001f
#define NSPLIT 16
#define NCHUNK NSPLIT        // 16 partial lists per row
#define TILE 64
#define NTILE ((NN / NSPLIT) / TILE)   // 8 tiles of 64 candidates per block
#define PBLK (8 * 2 * KP1 * 16)        // 2816 floats = 11264 B per block, contiguous

using short8 = __attribute__((ext_vector_type(8))) short;
using f32x4 = __attribute__((ext_vector_type(4))) float;

__device__ inline ushort f2bf(float f) {
    __hip_bfloat16 b = __float2bfloat16(f);
    return *reinterpret_cast<ushort*>(&b);
}
__device__ inline float bf2f(ushort u) {
    unsigned v = (unsigned)u << 16;
    union { unsigned u; float f; } c; c.u = v; return c.f;
}

// ---------------- Kernel 0: pre-split W1, W2 into hi/lo bf16 (layout unchanged: [col][k])
__global__ __launch_bounds__(256) void wsplit_kernel(
    const float* __restrict__ W1, const float* __restrict__ W2,
    ushort* __restrict__ W1h, ushort* __restrict__ W1l,
    ushort* __restrict__ W2h, ushort* __restrict__ W2l)
{
    const int bid = blockIdx.x;
    const float* src; ushort *dh, *dl; int base;
    if (bid < 64) { src = W1; dh = W1h; dl = W1l; base = bid * 1024; }
    else          { src = W2; dh = W2h; dl = W2l; base = (bid - 64) * 1024; }
    const int i = base + threadIdx.x * 4;
    float4 f = *reinterpret_cast<const float4*>(src + i);
    ushort h[4], lo[4];
    float fv[4] = {f.x, f.y, f.z, f.w};
#pragma unroll
    for (int j = 0; j < 4; ++j) {
        h[j] = f2bf(fv[j]);
        lo[j] = f2bf(fv[j] - bf2f(h[j]));
    }
    *reinterpret_cast<uint2*>(dh + i) = *reinterpret_cast<uint2*>(h);
    *reinterpret_cast<uint2*>(dl + i) = *reinterpret_cast<uint2*>(lo);
}

// ---------------- Kernel 1: split-bf16 MFMA MLP. Block = 32 rows x 128 cols, 4 waves.
// Outputs: xb = bf16(x), sqb = ||bf16(x)||^2
__global__ __launch_bounds__(256) void mlp_kernel(
    const float* __restrict__ s, const ushort* __restrict__ W1h,
    const ushort* __restrict__ W1l, const float* __restrict__ b1,
    const ushort* __restrict__ W2h, const ushort* __restrict__ W2l,
    const float* __restrict__ b2, __hip_bfloat16* __restrict__ xb,
    float* __restrict__ sqb)
{
    __shared__ __align__(16) ushort sbh[2][32 * 32];
    __shared__ __align__(16) ushort sbl[2][32 * 32];
    __shared__ __align__(16) ushort hbh[32 * 128];
    __shared__ __align__(16) ushort hbl[32 * 128];
    __shared__ __align__(16) ushort xtile[32 * 128];
    __shared__ float sqpart[4 * 32];

    const int t = threadIdx.x;
    const int w = t >> 6, l = t & 63;
    const int lc = l & 15, c4 = l >> 4;
    const int rb = blockIdx.x * 32;
    const int cb = w * 32;

    const int srow = t >> 3, skq = t & 7;
    const int ssl = ((skq >> 1) + (srow >> 2)) & 3;
    const int sByte = srow * 64 + (ssl ^ (srow & 3)) * 16 + (skq & 1) * 8;
    const float* sgbase = s + (size_t)(rb + srow) * SD + skq * 4;

    float4 sf;
#define STAGE_LOAD_S(kt_) sf = *reinterpret_cast<const float4*>(sgbase + (kt_) * 32)
#define STAGE_WRITE_S(b_) do { \
    float fv_[4] = {sf.x, sf.y, sf.z, sf.w}; \
    ushort h_[4], lo_[4]; \
    _Pragma("unroll") \
    for (int j_ = 0; j_ < 4; ++j_) { \
        h_[j_] = f2bf(fv_[j_]); \
        lo_[j_] = f2bf(fv_[j_] - bf2f(h_[j_])); \
    } \
    *reinterpret_cast<uint2*>(reinterpret_cast<char*>(sbh[b_]) + sByte) = *reinterpret_cast<uint2*>(h_); \
    *reinterpret_cast<uint2*>(reinterpret_cast<char*>(sbl[b_]) + sByte) = *reinterpret_cast<uint2*>(lo_); \
} while (0)

    int aByte[2];
#pragma unroll
    for (int rt = 0; rt < 2; ++rt) {
        int row = rt * 16 + lc;
        int sl = ((c4 + (row >> 2)) & 3) ^ (row & 3);
        aByte[rt] = row * 64 + sl * 16;
    }

    const ushort* w1hp[2]; const ushort* w1lp[2];
#pragma unroll
    for (int ct = 0; ct < 2; ++ct) {
        int col = cb + ct * 16 + lc;
        w1hp[ct] = W1h + (size_t)col * SD + c4 * 8;
        w1lp[ct] = W1l + (size_t)col * SD + c4 * 8;
    }

    f32x4 acc1[2][2];
#pragma unroll
    for (int rt = 0; rt < 2; ++rt)
#pragma unroll
        for (int ct = 0; ct < 2; ++ct) acc1[rt][ct] = {0.f, 0.f, 0.f, 0.f};

    STAGE_LOAD_S(0);
    STAGE_WRITE_S(0);
    short8 bh[2], bl[2], nbh[2], nbl[2];
#pragma unroll
    for (int ct = 0; ct < 2; ++ct) {
        bh[ct] = *reinterpret_cast<const short8*>(w1hp[ct]);
        bl[ct] = *reinterpret_cast<const short8*>(w1lp[ct]);
    }

    for (int kt = 0; kt < 16; ++kt) {
        __syncthreads();
        if (kt < 15) STAGE_LOAD_S(kt + 1);
        short8 ah[2], al[2];
#pragma unroll
        for (int rt = 0; rt < 2; ++rt) {
            ah[rt] = *reinterpret_cast<const short8*>(
                reinterpret_cast<char*>(sbh[kt & 1]) + aByte[rt]);
            al[rt] = *reinterpret_cast<const short8*>(
                reinterpret_cast<char*>(sbl[kt & 1]) + aByte[rt]);
        }
        if (kt < 15) {
#pragma unroll
            for (int ct = 0; ct < 2; ++ct) {
                nbh[ct] = *reinterpret_cast<const short8*>(w1hp[ct] + (kt + 1) * 32);
                nbl[ct] = *reinterpret_cast<const short8*>(w1lp[ct] + (kt + 1) * 32);
            }
        }
#pragma unroll
        for (int rt = 0; rt < 2; ++rt)
#pragma unroll
            for (int ct = 0; ct < 2; ++ct) {
                acc1[rt][ct] = __builtin_amdgcn_mfma_f32_16x16x32_bf16(ah[rt], bh[ct], acc1[rt][ct], 0, 0, 0);
                acc1[rt][ct] = __builtin_amdgcn_mfma_f32_16x16x32_bf16(ah[rt], bl[ct], acc1[rt][ct], 0, 0, 0);
                acc1[rt][ct] = __builtin_amdgcn_mfma_f32_16x16x32_bf16(al[rt], bh[ct], acc1[rt][ct], 0, 0, 0);
            }
        if (kt < 15) {
            STAGE_WRITE_S((kt + 1) & 1);
#pragma unroll
            for (int ct = 0; ct < 2; ++ct) { bh[ct] = nbh[ct]; bl[ct] = nbl[ct]; }
        }
    }

    float b1v[2];
#pragma unroll
    for (int ct = 0; ct < 2; ++ct) b1v[ct] = b1[cb + ct * 16 + lc];
#pragma unroll
    for (int rt = 0; rt < 2; ++rt)
#pragma unroll
        for (int ct = 0; ct < 2; ++ct)
#pragma unroll
            for (int reg = 0; reg < 4; ++reg) {
                float v = fmaxf(acc1[rt][ct][reg] + b1v[ct], 0.f);
                ushort hh = f2bf(v);
                ushort hl = f2bf(v - bf2f(hh));
                int row = rt * 16 + c4 * 4 + reg;
                int kcol = cb + ct * 16 + lc;
                int sl = (kcol >> 3) ^ (row & 15);
                int byte = row * 256 + sl * 16 + (kcol & 7) * 2;
                *reinterpret_cast<ushort*>(reinterpret_cast<char*>(hbh) + byte) = hh;
                *reinterpret_cast<ushort*>(reinterpret_cast<char*>(hbl) + byte) = hl;
            }
    __syncthreads();

    f32x4 acc2[2][2];
#pragma unroll
    for (int rt = 0; rt < 2; ++rt)
#pragma unroll
        for (int ct = 0; ct < 2; ++ct) acc2[rt][ct] = {0.f, 0.f, 0.f, 0.f};

#pragma unroll
    for (int kt = 0; kt < 4; ++kt) {
        short8 ah[2], al[2];
#pragma unroll
        for (int rt = 0; rt < 2; ++rt) {
            int row = rt * 16 + lc;
            int sl = (kt * 4 + c4) ^ (row & 15);
            int byte = row * 256 + sl * 16;
            ah[rt] = *reinterpret_cast<const short8*>(reinterpret_cast<char*>(hbh) + byte);
            al[rt] = *reinterpret_cast<const short8*>(reinterpret_cast<char*>(hbl) + byte);
        }
        short8 wh[2], wl[2];
#pragma unroll
        for (int ct = 0; ct < 2; ++ct) {
            int col = cb + ct * 16 + lc;
            wh[ct] = *reinterpret_cast<const short8*>(W2h + (size_t)col * HID + kt * 32 + c4 * 8);
            wl[ct] = *reinterpret_cast<const short8*>(W2l + (size_t)col * HID + kt * 32 + c4 * 8);
        }
#pragma unroll
        for (int rt = 0; rt < 2; ++rt)
#pragma unroll
            for (int ct = 0; ct < 2; ++ct) {
                acc2[rt][ct] = __builtin_amdgcn_mfma_f32_16x16x32_bf16(ah[rt], wh[ct], acc2[rt][ct], 0, 0, 0);
                acc2[rt][ct] = __builtin_amdgcn_mfma_f32_16x16x32_bf16(ah[rt], wl[ct], acc2[rt][ct], 0, 0, 0);
                acc2[rt][ct] = __builtin_amdgcn_mfma_f32_16x16x32_bf16(al[rt], wh[ct], acc2[rt][ct], 0, 0, 0);
            }
    }

    float b2v[2];
#pragma unroll
    for (int ct = 0; ct < 2; ++ct) b2v[ct] = b2[cb + ct * 16 + lc];
    float p[8];
#pragma unroll
    for (int j = 0; j < 8; ++j) p[j] = 0.f;
#pragma unroll
    for (int rt = 0; rt < 2; ++rt)
#pragma unroll
        for (int ct = 0; ct < 2; ++ct)
#pragma unroll
            for (int reg = 0; reg < 4; ++reg) {
                float v = acc2[rt][ct][reg] + b2v[ct];
                ushort xv = f2bf(v);
                float xf = bf2f(xv);
                p[rt * 4 + reg] = fmaf(xf, xf, p[rt * 4 + reg]);
                int row = rt * 16 + c4 * 4 + reg;
                int e = cb + ct * 16 + lc;
                xtile[row * 128 + e] = xv;
            }
#pragma unroll
    for (int j = 0; j < 8; ++j) {
#pragma unroll
        for (int off = 8; off >= 1; off >>= 1) p[j] += __shfl_xor(p[j], off, 16);
    }
    if (lc == 0) {
#pragma unroll
        for (int rt = 0; rt < 2; ++rt)
#pragma unroll
            for (int reg = 0; reg < 4; ++reg)
                sqpart[w * 32 + rt * 16 + c4 * 4 + reg] = p[rt * 4 + reg];
    }
    __syncthreads();
    if (t < 32)
        sqb[rb + t] = sqpart[t] + sqpart[32 + t] + sqpart[64 + t] + sqpart[96 + t];
    const short8* xsv = reinterpret_cast<const short8*>(xtile);
    short8* xg = reinterpret_cast<short8*>(reinterpret_cast<ushort*>(xb) + (size_t)rb * DE);
    xg[t] = xsv[t];
    xg[t + 256] = xsv[t + 256];
}

// ---------------- Kernel 2: per-row top-11 of d2'' = sq[c]/2 - x_q.x_c.
// 512-thread / 8-wave blocks, 256 queries/block, 512 cands/block (r5 traffic shape,
// 2x the resident waves). B = negated queries, C-in = 0.5*sq[c] from LDS.
__global__ __launch_bounds__(512) void knn_kernel(
    const ushort* __restrict__ xs, const float* __restrict__ sqb,
    float* __restrict__ part)
{
    __shared__ __align__(16) ushort lbuf[2][TILE * DE];   // 2 x 16KB (merge overlays)
    __shared__ __align__(16) float sqs[NN / NSPLIT];      // 2KB

    const int bid = blockIdx.x;              // 512 = 32 row-groups x 16 cand-splits
    const int rid = bid >> 4, cid = bid & 15;
    const int t = threadIdx.x;
    const int w = t >> 6, l = t & 63;
    const int q16 = l & 15, lg = l >> 4;
    const int kk = lg * 8;
    const int qb = rid * 256 + w * 32;
    const int cstart = cid * (NN / NSPLIT);  // 512 candidates per block

    // B-frags: NEGATED queries (sign-bit XOR on packed bf16 pairs; exact)
    short8 bq[2][4];
#pragma unroll
    for (int qs = 0; qs < 2; ++qs)
#pragma unroll
        for (int kb = 0; kb < 4; ++kb) {
            bq[qs][kb] = *reinterpret_cast<const short8*>(
                xs + (size_t)(qb + qs * 16 + q16) * DE + kb * 32 + kk);
            unsigned* u = reinterpret_cast<unsigned*>(&bq[qs][kb]);
#pragma unroll
            for (int i = 0; i < 4; ++i) u[i] ^= 0x80008000u;
        }

    float m[2][KP1];
#pragma unroll
    for (int qs = 0; qs < 2; ++qs)
#pragma unroll
        for (int j = 0; j < KP1; ++j) m[qs][j] = 1e30f;

#define INS(qs_, v_) do { \
    float d2_ = (v_); \
    _Pragma("unroll") \
    for (int j_ = KP1 - 1; j_ >= 1; --j_) \
        m[qs_][j_] = __builtin_amdgcn_fmed3f(d2_, m[qs_][j_ - 1], m[qs_][j_]); \
    m[qs_][0] = fminf(d2_, m[qs_][0]); \
} while (0)

    // stage 0.5*sq for the block's candidate range once (exact exponent shift)
    if (t < 128) {
        float4 v = reinterpret_cast<const float4*>(sqb + cstart)[t];
        v.x *= 0.5f; v.y *= 0.5f; v.z *= 0.5f; v.w *= 0.5f;
        reinterpret_cast<float4*>(sqs)[t] = v;
    }

    // staging: thread t owns 2 16B slots s = t, t+512 of the 1024-slot (16KB) tile
    int gIdx[2], dIdx[2];
#pragma unroll
    for (int i = 0; i < 2; ++i) {
        int sl = t + 512 * i;
        int row = sl >> 4, col = sl & 15;
        gIdx[i] = row * DE + col * 8;                       // ushort units
        dIdx[i] = (row * 16 + (col ^ (row & 7))) * 8;
    }
    // A-frag base indices (row = q16 within a 16-cand subtile)
    int aIdx[4];
#pragma unroll
    for (int kb = 0; kb < 4; ++kb)
        aIdx[kb] = (q16 * 16 + ((kb * 4 + lg) ^ (q16 & 7))) * 8;

    short8 st[2];
#define STAGE_LOAD(tt_) do { \
    const ushort* sb_ = xs + (size_t)(cstart + (tt_) * TILE) * DE; \
    st[0] = *reinterpret_cast<const short8*>(sb_ + gIdx[0]); \
    st[1] = *reinterpret_cast<const short8*>(sb_ + gIdx[1]); \
} while (0)
#define STAGE_WRITE(nb_) do { \
    *reinterpret_cast<short8*>(&lbuf[nb_][dIdx[0]]) = st[0]; \
    *reinterpret_cast<short8*>(&lbuf[nb_][dIdx[1]]) = st[1]; \
} while (0)

    STAGE_LOAD(0);
    STAGE_WRITE(0);

    for (int tt = 0; tt < NTILE; ++tt) {
        __syncthreads();                     // publishes lbuf[tt&1] (and sqs on tt=0)
        if (tt + 1 < NTILE) STAGE_LOAD(tt + 1);
        const ushort* lb = lbuf[tt & 1];
#pragma unroll
        for (int cs = 0; cs < 4; ++cs) {     // 16-cand subtiles
            short8 fa[4];
#pragma unroll
            for (int kb = 0; kb < 4; ++kb)
                fa[kb] = *reinterpret_cast<const short8*>(lb + cs * 2048 + aIdx[kb]);
            float4 sv = *reinterpret_cast<const float4*>(sqs + tt * TILE + cs * 16 + lg * 4);
#pragma unroll
            for (int qs = 0; qs < 2; ++qs) {
                f32x4 acc = {sv.x, sv.y, sv.z, sv.w};   // C-in = sq[c]/2; B = -x_q
#pragma unroll
                for (int kb = 0; kb < 4; ++kb)
                    acc = __builtin_amdgcn_mfma_f32_16x16x32_bf16(fa[kb], bq[qs][kb], acc, 0, 0, 0);
                INS(qs, acc[0]);
                INS(qs, acc[1]);
                INS(qs, acc[2]);
                INS(qs, acc[3]);
            }
        }
        if (tt + 1 < NTILE) STAGE_WRITE((tt + 1) & 1);  // buffer freed by this iter's sync
    }
#undef STAGE_LOAD
#undef STAGE_WRITE
#undef INS

    // ---- in-kernel lane-group merge, 2 phases (qs); block-contiguous part write
    float* mb = reinterpret_cast<float*>(lbuf);   // [8w][4lg][11][16] floats = 22528 B
    float* pout = part + (size_t)bid * PBLK;
#pragma unroll
    for (int qs = 0; qs < 2; ++qs) {
        __syncthreads();                     // lbuf free / previous phase done
#pragma unroll
        for (int j = 0; j < KP1; ++j)
            mb[((w * 4 + lg) * KP1 + j) * 16 + q16] = m[qs][j];
        __syncthreads();
        if (l < 16) {                        // lanes 0..15: q16 == l
            float mm[KP1];
#pragma unroll
            for (int j = 0; j < KP1; ++j)
                mm[j] = mb[((w * 4 + 0) * KP1 + j) * 16 + l];
#pragma unroll
            for (int g = 1; g < 4; ++g)
#pragma unroll
                for (int j = 0; j < KP1; ++j) {
                    float d2 = mb[((w * 4 + g) * KP1 + j) * 16 + l];
#pragma unroll
                    for (int jj = KP1 - 1; jj >= 1; --jj)
                        mm[jj] = __builtin_amdgcn_fmed3f(d2, mm[jj - 1], mm[jj]);
                    mm[0] = fminf(d2, mm[0]);
                }
#pragma unroll
            for (int j = 0; j < KP1; ++j)
                pout[((w * 2 + qs) * KP1 + j) * 16 + l] = mm[j];
        }
    }
}

// ---------------- Kernel 3: merge 16 partial lists (block-contiguous layout) -> sumk;
// dist^2 = 2*m + sqq (m holds sq[c]/2 - dot).
__global__ __launch_bounds__(256) void merge_kernel(
    const float* __restrict__ part, const float* __restrict__ sqb,
    float* __restrict__ sumk, float* __restrict__ psum)
{
    const int row = blockIdx.x * 256 + threadIdx.x;
    const int rid = row >> 8;                                  // 256 queries per knn block
    const int sub = ((row >> 5) & 7) * 2 + ((row >> 4) & 1);   // w*2+qs
    const int lane = row & 15;
    const float* pbase = part + (size_t)rid * 16 * PBLK + sub * (KP1 * 16) + lane;

    float m[KP1];
#pragma unroll
    for (int j = 0; j < KP1; ++j) m[j] = 1e30f;
#pragma unroll 4
    for (int ch = 0; ch < NCHUNK; ++ch) {
        const float* pc = pbase + ch * PBLK;
#pragma unroll
        for (int j = 0; j < KP1; ++j) {
            float d2 = pc[j * 16];
#pragma unroll
            for (int jj = KP1 - 1; jj >= 1; --jj)
                m[jj] = __builtin_amdgcn_fmed3f(d2, m[jj - 1], m[jj]);
            m[0] = fminf(d2, m[0]);
        }
    }
    const float sqq = sqb[row];
    float sum = 0.f;
#pragma unroll
    for (int j = 1; j < KP1; ++j)
        sum += sqrtf(fmaxf(fmaf(2.f, m[j], sqq), 1e-12f));
    sumk[row] = sum;

    float p = sum;
#pragma unroll
    for (int off = 32; off >= 1; off >>= 1) p += __shfl_xor(p, off, 64);
    __shared__ float red[4];
    if ((threadIdx.x & 63) == 0) red[threadIdx.x >> 6] = p;
    __syncthreads();
    if (threadIdx.x == 0) psum[blockIdx.x] = red[0] + red[1] + red[2] + red[3];
}

// ---------------- Kernel 4: mean over 32 partials -> q = EPS * mean^2
__global__ void reduce_kernel(const float* __restrict__ psum, float* __restrict__ qv)
{
    const int t = threadIdx.x;
    float p = (t < 32) ? psum[t] : 0.f;
#pragma unroll
    for (int off = 32; off >= 1; off >>= 1) p += __shfl_xor(p, off, 64);
    if (t == 0) {
        float mean = p * (1.0f / NN);
        qv[0] = EPSF * mean * mean;
    }
}

// ---------------- Kernel 5: out = q / (s^2 + q)
__global__ __launch_bounds__(256) void final_kernel(
    const float* __restrict__ sumk, const float* __restrict__ qv,
    float* __restrict__ out)
{
    const int i = blockIdx.x * 256 + threadIdx.x;
    const float qq = qv[0];
    const float sv = sumk[i];
    out[i] = qq / (fmaf(sv, sv, qq));
}

extern "C" void kernel_launch(void* const* d_in, const int* in_sizes, int n_in,
                              void* d_out, int out_size, void* d_ws, size_t ws_size,
                              hipStream_t stream)
{
    const float* s  = (const float*)d_in[0];
    const float* W1 = (const float*)d_in[1];
    const float* b1 = (const float*)d_in[2];
    const float* W2 = (const float*)d_in[3];
    const float* b2 = (const float*)d_in[4];
    float* out = (float*)d_out;

    char* ws = (char*)d_ws;
    __hip_bfloat16* xb = (__hip_bfloat16*)ws;                       // 2 MB
    float* sqb  = (float*)(ws + (size_t)NN * DE * 2);               // 32 KB
    float* part = sqb + NN;                                         // 512*11264B = 5.6 MB
    float* sumk = part + (size_t)512 * PBLK;                        // 32 KB
    float* psum = sumk + NN;                                        // 128 B
    float* qv   = psum + 32;                                        // 4 B
    ushort* W1h = (ushort*)(qv + 1);                                // 128 KB
    ushort* W1l = W1h + (size_t)HID * SD;                           // 128 KB
    ushort* W2h = W1l + (size_t)HID * SD;                           // 32 KB
    ushort* W2l = W2h + (size_t)DE * HID;                           // 32 KB

    wsplit_kernel<<<80, 256, 0, stream>>>(W1, W2, W1h, W1l, W2h, W2l);
    mlp_kernel<<<NN / 32, 256, 0, stream>>>(s, W1h, W1l, b1, W2h, W2l, b2, xb, sqb);
    knn_kernel<<<(NN / 256) * NSPLIT, 512, 0, stream>>>((const ushort*)xb, sqb, part);
    merge_kernel<<<NN / 256, 256, 0, stream>>>(part, sqb, sumk, psum);
    reduce_kernel<<<1, 64, 0, stream>>>(psum, qv);
    final_kernel<<<NN / 256, 256, 0, stream>>>(sumk, qv, out);
}